// Round 1
// 489.114 us; speedup vs baseline: 3.8124x; 3.8124x over previous
//
#include <hip/hip_runtime.h>
#include <hip/hip_bf16.h>

// EncoderAttention4 v2: agent-batched, B-loaded-once MFMA pipeline for MI355X.
// B=65536, NEGO=48, NADO=24, NADOAG=5, E=256, H=4, AD=64. Out: (B,112) fp32.
//
// Key changes vs v1:
//  - 16 batch rows / block (4096 blocks), all 5 agents batched into single
//    80-row GEMMs for ado0/ado1/key/lat -> every weight B-fragment is loaded
//    from global exactly ONCE per wave per GEMM (was: once per 16-row tile,
//    ~6x global weight traffic).
//  - exact softmax (all 5 logits available at once), lat aggregated in regs.
//  - 9 barrier phases (was ~25).
//  - nontemporal, fully-coalesced float4 output stores (keep L2 clean so the
//    737KB weight workspace stays L2-resident; kills the HBM re-fetch).

typedef __bf16 bf16x8 __attribute__((ext_vector_type(8)));
typedef __bf16 bf16x4 __attribute__((ext_vector_type(4)));
typedef float  f32x4  __attribute__((ext_vector_type(4)));

// Workspace layout (bf16 elements), unchanged from v1.
#define OFF_EGO0 0        // [256][64]  (K=48 padded to 64)
#define OFF_EGO1 16384    // [256][256]
#define OFF_ADO0 81920    // [256][32]  (K=25 padded to 32)
#define OFF_ADO1 90112    // [256][256]
#define OFF_SEL  155648   // [256][256] col c -> head c>>6, d c&63
#define OFF_KEY  221184
#define OFF_LAT  286720
#define OFF_PROJ 352256   // [64][256]
#define WS_ELEMS 368640

__global__ __launch_bounds__(256) void prep_weights(
    const float* __restrict__ ew0, const float* __restrict__ ew1,
    const float* __restrict__ aw0, const float* __restrict__ aw1,
    const float* __restrict__ keyw, const float* __restrict__ selw,
    const float* __restrict__ latw, const float* __restrict__ projw,
    __bf16* __restrict__ ws)
{
  int i = blockIdx.x * 256 + threadIdx.x;
  if (i >= WS_ELEMS) return;
  float v;
  if (i < OFF_EGO1)      { int j=i;          int c=j>>6, k=j&63;  v = (k<48) ? ew0[k*256+c] : 0.f; }
  else if (i < OFF_ADO0) { int j=i-OFF_EGO1; int c=j>>8, k=j&255; v = ew1[k*256+c]; }
  else if (i < OFF_ADO1) { int j=i-OFF_ADO0; int c=j>>5, k=j&31;  v = (k<25) ? aw0[k*256+c] : 0.f; }
  else if (i < OFF_SEL)  { int j=i-OFF_ADO1; int c=j>>8, k=j&255; v = aw1[k*256+c]; }
  else if (i < OFF_KEY)  { int j=i-OFF_SEL;  int c=j>>8, k=j&255; v = selw[(c>>6)*16384 + k*64 + (c&63)]; }
  else if (i < OFF_LAT)  { int j=i-OFF_KEY;  int c=j>>8, k=j&255; v = keyw[(c>>6)*16384 + k*64 + (c&63)]; }
  else if (i < OFF_PROJ) { int j=i-OFF_LAT;  int c=j>>8, k=j&255; v = latw[(c>>6)*16384 + k*64 + (c&63)]; }
  else                   { int j=i-OFF_PROJ; int c=j>>8, k=j&255; v = projw[k*64+c]; }
  ws[i] = (__bf16)v;
}

// XOR-swizzled LDS accessors. byte ^= (row&7)<<4 (bijective: mask is a
// function of higher address bits, Feistel-style).
__device__ __forceinline__ bf16x8 lds_loadA(const __bf16* base, int row, int kByte, int rowBytes) {
  int off = (row * rowBytes + kByte) ^ ((row & 7) << 4);
  return *reinterpret_cast<const bf16x8*>(reinterpret_cast<const char*>(base) + off);
}
__device__ __forceinline__ void lds_store_bf16(__bf16* base, int row, int col, __bf16 v) {
  int off = (row * 512 + col * 2) ^ ((row & 7) << 4);  // 256-col tiles only
  *reinterpret_cast<__bf16*>(reinterpret_cast<char*>(base) + off) = v;
}

// LDS pool layout (bytes). Aliased regions with phase-disjoint lifetimes:
//   P_ADO2  [0,40960)      : ado activations, 80x512 swz (written ph4/ph6)
//     P_EGOIN [0,2048)     : ego input 16x128 swz   (dead after ph2)
//     P_EGOH1 [2048,10240) : ego hidden1 16x512 swz (dead after ph3)
//     P_ADOIN [24576,29696): ado input 80x64 swz    (dead after ph5; inside
//                            ADO2 rows 48.., which are only written in ph6)
//   P_EGOH2 [40960,49152)  : ego hidden2 16x512 swz (dead after ph4 'sel')
//     P_PROJIN (same addr) : proj input 16x512 swz  (written ph7)
//   P_H1    [49152,73728)  : ado hidden1 half, 48x512 swz (dead after ph6)
//   P_OUT   [73728,77824)  : proj output fp32 16x64
#define P_ADO2   0
#define P_EGOIN  0
#define P_EGOH1  2048
#define P_ADOIN  24576
#define P_EGOH2  40960
#define P_PROJIN 40960
#define P_H1     49152
#define P_OUT    73728
#define POOL_BYTES 77824   // 76KB -> 2 blocks/CU (152KB of 160KB)

// C(out 16R rows x 64 cols/wave) = act(A @ WT^T + bias).
// B-loaded-once: each B fragment read exactly once per wave; A fragments for
// all R row-tiles held in regs per kb (ct-pair halves keep acc <= R*2 f32x4).
template<int KP, int R, bool ACT>
__device__ __forceinline__ void gemm_block(const __bf16* __restrict__ sA, int aRow0,
                                           __bf16* __restrict__ sC, int cRow0,
                                           const __bf16* __restrict__ WT,
                                           const float* __restrict__ bias,
                                           int w, int lr, int lg)
{
  constexpr int NKB = KP / 32;
  #pragma unroll
  for (int cth = 0; cth < 2; ++cth) {
    f32x4 acc[R][2];
    #pragma unroll
    for (int t = 0; t < R; ++t) {
      acc[t][0] = f32x4{0.f,0.f,0.f,0.f};
      acc[t][1] = f32x4{0.f,0.f,0.f,0.f};
    }
    #pragma unroll
    for (int kb = 0; kb < NKB; ++kb) {
      bf16x8 af[R];
      #pragma unroll
      for (int t = 0; t < R; ++t)
        af[t] = lds_loadA(sA, aRow0 + t*16 + lr, kb*64 + lg*16, KP*2);
      #pragma unroll
      for (int c2 = 0; c2 < 2; ++c2) {
        const int col = w*64 + (cth*2 + c2)*16 + lr;
        bf16x8 bfr = *reinterpret_cast<const bf16x8*>(WT + col*KP + kb*32 + lg*8);
        #pragma unroll
        for (int t = 0; t < R; ++t)
          acc[t][c2] = __builtin_amdgcn_mfma_f32_16x16x32_bf16(af[t], bfr, acc[t][c2], 0, 0, 0);
      }
    }
    #pragma unroll
    for (int c2 = 0; c2 < 2; ++c2) {
      const int col = w*64 + (cth*2 + c2)*16 + lr;
      const float bv = bias[col];
      #pragma unroll
      for (int t = 0; t < R; ++t) {
        #pragma unroll
        for (int e = 0; e < 4; ++e) {
          float x = acc[t][c2][e] + bv;
          if (ACT) x = x > 0.f ? x : 0.01f * x;
          lds_store_bf16(sC, cRow0 + t*16 + lg*4 + e, col, (__bf16)x);
        }
      }
    }
  }
}

__global__ __launch_bounds__(256) void fused_kernel(
    const float* __restrict__ obs,
    const float* __restrict__ eb0, const float* __restrict__ eb1,
    const float* __restrict__ ab0, const float* __restrict__ ab1,
    const float* __restrict__ latb, const float* __restrict__ projb,
    const __bf16* __restrict__ ws,
    float* __restrict__ out)
{
  const int tid = threadIdx.x;
  const int w  = tid >> 6;   // wave = head
  const int l  = tid & 63;
  const int lr = l & 15;
  const int lg = l >> 4;
  const int b0 = blockIdx.x * 16;

  __shared__ __align__(16) char pool[POOL_BYTES];
  __bf16* sEgoIn = reinterpret_cast<__bf16*>(pool + P_EGOIN);
  __bf16* sEgoH1 = reinterpret_cast<__bf16*>(pool + P_EGOH1);
  __bf16* sAdoIn = reinterpret_cast<__bf16*>(pool + P_ADOIN);
  __bf16* sEgoH2 = reinterpret_cast<__bf16*>(pool + P_EGOH2);
  __bf16* sProj  = reinterpret_cast<__bf16*>(pool + P_PROJIN);
  __bf16* sAdo2  = reinterpret_cast<__bf16*>(pool + P_ADO2);
  __bf16* sH1    = reinterpret_cast<__bf16*>(pool + P_H1);
  float*  sOutF  = reinterpret_cast<float*>(pool + P_OUT);

  // ---- phase 1: stage. obs read exactly once; passthrough out[:, :48] NT.
  {
    if (tid < 192) {
      int row = tid / 12, c4 = tid % 12;
      f32x4 v = *reinterpret_cast<const f32x4*>(obs + (size_t)(b0+row)*168 + c4*4);
      __builtin_nontemporal_store(v,
          reinterpret_cast<f32x4*>(out + (size_t)(b0+row)*112 + c4*4));
      bf16x4 bv = { (__bf16)v[0], (__bf16)v[1], (__bf16)v[2], (__bf16)v[3] };
      int off = (row*128 + c4*8) ^ ((row&7)<<4);
      *reinterpret_cast<bf16x4*>(reinterpret_cast<char*>(sEgoIn) + off) = bv;
    } else {
      int t = tid - 192;               // 64 threads: zero-pad ego cols 48..63
      int row = t >> 2, ch = t & 3;
      bf16x4 z = {};
      int off = (row*128 + 96 + ch*8) ^ ((row&7)<<4);
      *reinterpret_cast<bf16x4*>(reinterpret_cast<char*>(sEgoIn) + off) = z;
    }
    // ado input: 80 lds rows (agent n*16 + r) x 32 cols (24 gathered + tid + 0s)
    if (tid < 240) {
      int ldsrow = tid / 3, p = tid % 3;
      int n = ldsrow >> 4, r = ldsrow & 15;
      const float* orow = obs + (size_t)(b0+r)*168 + 48;
      bf16x8 v;
      #pragma unroll
      for (int j = 0; j < 8; ++j) v[j] = (__bf16)orow[(p*8+j)*5 + n];
      int off = (ldsrow*64 + p*16) ^ ((ldsrow&7)<<4);
      *reinterpret_cast<bf16x8*>(reinterpret_cast<char*>(sAdoIn) + off) = v;
    }
    if (tid < 80) {                    // cols 24..31: teamid + zero pad
      int n = tid >> 4;
      bf16x8 v = {};
      v[0] = (__bf16)((n >= 2) ? 1.0f : 0.0f);   // team_ids[1:6] = 0,0,1,1,1
      int off = (tid*64 + 48) ^ ((tid&7)<<4);
      *reinterpret_cast<bf16x8*>(reinterpret_cast<char*>(sAdoIn) + off) = v;
    }
  }
  __syncthreads();

  // ---- phase 2: ego0 + ado0 (agents 0..2 -> sH1 rows 0..47)
  gemm_block<64, 1, true>(sEgoIn, 0, sEgoH1, 0, ws + OFF_EGO0, eb0, w, lr, lg);
  gemm_block<32, 3, true>(sAdoIn, 0, sH1,    0, ws + OFF_ADO0, ab0, w, lr, lg);
  __syncthreads();

  // ---- phase 3: ego1
  gemm_block<256, 1, true>(sEgoH1, 0, sEgoH2, 0, ws + OFF_EGO1, eb1, w, lr, lg);
  __syncthreads();

  // ---- phase 4: sel (regs) + ado1 agents 0..2 -> sAdo2 rows 0..47
  f32x4 slct[4];
  {
    const __bf16* WT = ws + OFF_SEL;
    #pragma unroll
    for (int ct = 0; ct < 4; ++ct) slct[ct] = f32x4{0.f,0.f,0.f,0.f};
    #pragma unroll
    for (int kb = 0; kb < 8; ++kb) {
      bf16x8 af = lds_loadA(sEgoH2, lr, kb*64 + lg*16, 512);
      #pragma unroll
      for (int ct = 0; ct < 4; ++ct) {
        bf16x8 bfr = *reinterpret_cast<const bf16x8*>(WT + (w*64+ct*16+lr)*256 + kb*32 + lg*8);
        slct[ct] = __builtin_amdgcn_mfma_f32_16x16x32_bf16(af, bfr, slct[ct], 0, 0, 0);
      }
    }
  }
  gemm_block<256, 3, true>(sH1, 0, sAdo2, 0, ws + OFF_ADO1, ab1, w, lr, lg);
  __syncthreads();

  // ---- phase 5: ado0 agents 3..4 -> sH1 rows 0..31
  gemm_block<32, 2, true>(sAdoIn, 48, sH1, 0, ws + OFF_ADO0, ab0, w, lr, lg);
  __syncthreads();

  // ---- phase 6: ado1 agents 3..4 -> sAdo2 rows 48..79
  gemm_block<256, 2, true>(sH1, 0, sAdo2, 48, ws + OFF_ADO1, ab1, w, lr, lg);
  __syncthreads();

  // ---- phase 7: key pass -> exact softmax -> lat pass (agg in regs)
  f32x4 part[5];
  #pragma unroll
  for (int n = 0; n < 5; ++n) part[n] = f32x4{0.f,0.f,0.f,0.f};
  {
    const __bf16* WK = ws + OFF_KEY;
    #pragma unroll
    for (int cth = 0; cth < 2; ++cth) {
      f32x4 kacc[5][2];
      #pragma unroll
      for (int n = 0; n < 5; ++n) {
        kacc[n][0] = f32x4{0.f,0.f,0.f,0.f};
        kacc[n][1] = f32x4{0.f,0.f,0.f,0.f};
      }
      #pragma unroll
      for (int kb = 0; kb < 8; ++kb) {
        bf16x8 af[5];
        #pragma unroll
        for (int n = 0; n < 5; ++n)
          af[n] = lds_loadA(sAdo2, n*16 + lr, kb*64 + lg*16, 512);
        #pragma unroll
        for (int c2 = 0; c2 < 2; ++c2) {
          const int col = w*64 + (cth*2 + c2)*16 + lr;
          bf16x8 bk = *reinterpret_cast<const bf16x8*>(WK + col*256 + kb*32 + lg*8);
          #pragma unroll
          for (int n = 0; n < 5; ++n)
            kacc[n][c2] = __builtin_amdgcn_mfma_f32_16x16x32_bf16(af[n], bk, kacc[n][c2], 0, 0, 0);
        }
      }
      #pragma unroll
      for (int c2 = 0; c2 < 2; ++c2)
        #pragma unroll
        for (int n = 0; n < 5; ++n)
          part[n] += kacc[n][c2] * slct[cth*2 + c2];
    }
  }
  // reduce logits over lr lanes (d = ct*16+lr already summed over ct in-lane)
  #pragma unroll
  for (int n = 0; n < 5; ++n) {
    #pragma unroll
    for (int m = 1; m < 16; m <<= 1) {
      part[n][0] += __shfl_xor(part[n][0], m);
      part[n][1] += __shfl_xor(part[n][1], m);
      part[n][2] += __shfl_xor(part[n][2], m);
      part[n][3] += __shfl_xor(part[n][3], m);
    }
  }
  // exact softmax over the 5 agents, rows lg*4+e
  f32x4 p[5];
  {
    #pragma unroll
    for (int n = 0; n < 5; ++n) part[n] *= 0.125f;   // / sqrt(64)
    f32x4 mx = part[0];
    #pragma unroll
    for (int n = 1; n < 5; ++n)
      #pragma unroll
      for (int e = 0; e < 4; ++e) mx[e] = fmaxf(mx[e], part[n][e]);
    f32x4 s = f32x4{0.f,0.f,0.f,0.f};
    #pragma unroll
    for (int n = 0; n < 5; ++n) {
      #pragma unroll
      for (int e = 0; e < 4; ++e) p[n][e] = __expf(part[n][e] - mx[e]);
      s += p[n];
    }
    f32x4 inv;
    #pragma unroll
    for (int e = 0; e < 4; ++e) inv[e] = 1.0f / s[e];
    #pragma unroll
    for (int n = 0; n < 5; ++n) p[n] *= inv;
  }
  // lat pass: weighted aggregation directly in registers
  f32x4 agg[4];
  #pragma unroll
  for (int ct = 0; ct < 4; ++ct) agg[ct] = f32x4{0.f,0.f,0.f,0.f};
  {
    const __bf16* WL = ws + OFF_LAT;
    #pragma unroll
    for (int cth = 0; cth < 2; ++cth) {
      f32x4 lacc[5][2];
      #pragma unroll
      for (int n = 0; n < 5; ++n) {
        lacc[n][0] = f32x4{0.f,0.f,0.f,0.f};
        lacc[n][1] = f32x4{0.f,0.f,0.f,0.f};
      }
      #pragma unroll
      for (int kb = 0; kb < 8; ++kb) {
        bf16x8 af[5];
        #pragma unroll
        for (int n = 0; n < 5; ++n)
          af[n] = lds_loadA(sAdo2, n*16 + lr, kb*64 + lg*16, 512);
        #pragma unroll
        for (int c2 = 0; c2 < 2; ++c2) {
          const int col = w*64 + (cth*2 + c2)*16 + lr;
          bf16x8 bl = *reinterpret_cast<const bf16x8*>(WL + col*256 + kb*32 + lg*8);
          #pragma unroll
          for (int n = 0; n < 5; ++n)
            lacc[n][c2] = __builtin_amdgcn_mfma_f32_16x16x32_bf16(af[n], bl, lacc[n][c2], 0, 0, 0);
        }
      }
      #pragma unroll
      for (int c2 = 0; c2 < 2; ++c2) {
        const int ct = cth*2 + c2;
        const float lb = latb[w*64 + ct*16 + lr];
        #pragma unroll
        for (int n = 0; n < 5; ++n) {
          #pragma unroll
          for (int e = 0; e < 4; ++e) {
            float x = lacc[n][c2][e] + lb;
            x = x > 0.f ? x : 0.01f * x;
            agg[ct][e] += p[n][e] * x;
          }
        }
      }
    }
  }
  // agg -> sProj (proj input, bf16 swz). Overwrites sEgoH2 (dead).
  #pragma unroll
  for (int ct = 0; ct < 4; ++ct)
    #pragma unroll
    for (int e = 0; e < 4; ++e)
      lds_store_bf16(sProj, lg*4 + e, w*64 + ct*16 + lr, (__bf16)agg[ct][e]);
  __syncthreads();

  // ---- phase 8: proj (16x256)@(256x64); wave w -> cols w*16..w*16+15
  {
    const __bf16* WT = ws + OFF_PROJ;
    f32x4 pacc = f32x4{0.f,0.f,0.f,0.f};
    #pragma unroll
    for (int kb = 0; kb < 8; ++kb) {
      bf16x8 af = lds_loadA(sProj, lr, kb*64 + lg*16, 512);
      bf16x8 bfr = *reinterpret_cast<const bf16x8*>(WT + (w*16+lr)*256 + kb*32 + lg*8);
      pacc = __builtin_amdgcn_mfma_f32_16x16x32_bf16(af, bfr, pacc, 0, 0, 0);
    }
    const float pb = projb[w*16 + lr];
    #pragma unroll
    for (int e = 0; e < 4; ++e)
      sOutF[(lg*4 + e)*64 + w*16 + lr] = pacc[e] + pb;
  }
  __syncthreads();

  // ---- phase 9: coalesced NT float4 writes of out[:, 48:112]
  {
    int row = tid >> 4, q = tid & 15;
    f32x4 v = *reinterpret_cast<const f32x4*>(sOutF + row*64 + q*4);
    __builtin_nontemporal_store(v,
        reinterpret_cast<f32x4*>(out + (size_t)(b0+row)*112 + 48 + q*4));
  }
}

extern "C" void kernel_launch(void* const* d_in, const int* in_sizes, int n_in,
                              void* d_out, int out_size, void* d_ws, size_t ws_size,
                              hipStream_t stream) {
  const float* obs   = (const float*)d_in[0];
  const float* ew0   = (const float*)d_in[1];
  const float* eb0   = (const float*)d_in[2];
  const float* ew1   = (const float*)d_in[3];
  const float* eb1   = (const float*)d_in[4];
  const float* aw0   = (const float*)d_in[5];
  const float* ab0   = (const float*)d_in[6];
  const float* aw1   = (const float*)d_in[7];
  const float* ab1   = (const float*)d_in[8];
  const float* keyw  = (const float*)d_in[9];
  const float* selw  = (const float*)d_in[10];
  const float* latw  = (const float*)d_in[11];
  const float* latb  = (const float*)d_in[12];
  const float* projw = (const float*)d_in[13];
  const float* projb = (const float*)d_in[14];
  __bf16* ws = (__bf16*)d_ws;
  float* out = (float*)d_out;

  prep_weights<<<dim3((WS_ELEMS + 255)/256), dim3(256), 0, stream>>>(
      ew0, ew1, aw0, aw1, keyw, selw, latw, projw, ws);
  fused_kernel<<<dim3(65536/16), dim3(256), 0, stream>>>(
      obs, eb0, eb1, ab0, ab1, latb, projb, ws, out);
}

// Round 2
// 457.687 us; speedup vs baseline: 4.0742x; 1.0687x over previous
//
#include <hip/hip_runtime.h>
#include <hip/hip_bf16.h>

// EncoderAttention4 v3: 8-wave column-split blocks for latency hiding.
// B=65536, NEGO=48, NADO=24, NADOAG=5, E=256, H=4, AD=64. Out: (B,112) fp32.
//
// Changes vs v2 (which was latency-bound: MfmaUtil 12%, occupancy 12%,
// 2 blocks x 4 waves / CU, 9-phase serial chain):
//  - 512-thread blocks (8 waves), every 256-col GEMM column-split 2x:
//    wave w owns cols w*32 + c2*16 + lr. Per-wave MFMA chain halves
//    (~580 -> ~290), waves/CU double (8 -> 16). B-fragments still loaded
//    once per block. __launch_bounds__(512,4) forces VGPR<=128 so 2 blocks
//    (16 waves) are co-resident per CU.
//  - logit d=64 reduction now spans a wave pair (w, w^1): f32x4 partial
//    exchange through a 2.5KB LDS buffer aliased on the dead P_OUT region.
//  - staging: coalesced f32x4 obs->LDS copy, then all bf16 gathers read LDS
//    (kills the 1920 uncoalesced scalar global loads per block).
//  - 1/sqrt(AD) folded into slct at sel time.

typedef __bf16 bf16x8 __attribute__((ext_vector_type(8)));
typedef __bf16 bf16x4 __attribute__((ext_vector_type(4)));
typedef float  f32x4  __attribute__((ext_vector_type(4)));

// Workspace layout (bf16 elements), unchanged.
#define OFF_EGO0 0        // [256][64]  (K=48 padded to 64)
#define OFF_EGO1 16384    // [256][256]
#define OFF_ADO0 81920    // [256][32]  (K=25 padded to 32)
#define OFF_ADO1 90112    // [256][256]
#define OFF_SEL  155648   // [256][256] col c -> head c>>6, d c&63
#define OFF_KEY  221184
#define OFF_LAT  286720
#define OFF_PROJ 352256   // [64][256]
#define WS_ELEMS 368640

__global__ __launch_bounds__(256) void prep_weights(
    const float* __restrict__ ew0, const float* __restrict__ ew1,
    const float* __restrict__ aw0, const float* __restrict__ aw1,
    const float* __restrict__ keyw, const float* __restrict__ selw,
    const float* __restrict__ latw, const float* __restrict__ projw,
    __bf16* __restrict__ ws)
{
  int i = blockIdx.x * 256 + threadIdx.x;
  if (i >= WS_ELEMS) return;
  float v;
  if (i < OFF_EGO1)      { int j=i;          int c=j>>6, k=j&63;  v = (k<48) ? ew0[k*256+c] : 0.f; }
  else if (i < OFF_ADO0) { int j=i-OFF_EGO1; int c=j>>8, k=j&255; v = ew1[k*256+c]; }
  else if (i < OFF_ADO1) { int j=i-OFF_ADO0; int c=j>>5, k=j&31;  v = (k<25) ? aw0[k*256+c] : 0.f; }
  else if (i < OFF_SEL)  { int j=i-OFF_ADO1; int c=j>>8, k=j&255; v = aw1[k*256+c]; }
  else if (i < OFF_KEY)  { int j=i-OFF_SEL;  int c=j>>8, k=j&255; v = selw[(c>>6)*16384 + k*64 + (c&63)]; }
  else if (i < OFF_LAT)  { int j=i-OFF_KEY;  int c=j>>8, k=j&255; v = keyw[(c>>6)*16384 + k*64 + (c&63)]; }
  else if (i < OFF_PROJ) { int j=i-OFF_LAT;  int c=j>>8, k=j&255; v = latw[(c>>6)*16384 + k*64 + (c&63)]; }
  else                   { int j=i-OFF_PROJ; int c=j>>8, k=j&255; v = projw[k*64+c]; }
  ws[i] = (__bf16)v;
}

// XOR-swizzled LDS accessors. byte ^= (row&7)<<4.
__device__ __forceinline__ bf16x8 lds_loadA(const __bf16* base, int row, int kByte, int rowBytes) {
  int off = (row * rowBytes + kByte) ^ ((row & 7) << 4);
  return *reinterpret_cast<const bf16x8*>(reinterpret_cast<const char*>(base) + off);
}
__device__ __forceinline__ void lds_store_bf16(__bf16* base, int row, int col, __bf16 v) {
  int off = (row * 512 + col * 2) ^ ((row & 7) << 4);  // 256-col tiles only
  *reinterpret_cast<__bf16*>(reinterpret_cast<char*>(base) + off) = v;
}

// LDS pool (bytes). Aliased regions with phase-disjoint lifetimes:
//   P_ADO2  [0,40960)      : ado activations, 80x512 swz (written ph4/ph6)
//     P_EGOIN [0,2048)     : ego input 16x128 swz   (dead after ph2)
//     P_EGOH1 [2048,10240) : ego hidden1 16x512 swz (dead after ph3)
//     P_ADOIN [24576,29696): ado input 80x64 swz    (dead after ph5)
//   P_EGOH2 [40960,49152)  : ego hidden2 16x512 swz (dead after ph4 'sel')
//     P_PROJIN (same addr) : proj input 16x512 swz  (written ph7)
//   P_H1    [49152,73728)  : ado hidden1 half, 48x512 swz (dead after ph6)
//     P_OBSRAW (same addr) : raw fp32 obs 16x168    (dead after ph1b)
//   P_OUT   [73728,77824)  : logit exchange (ph7) then proj fp32 out (ph8)
#define P_ADO2   0
#define P_EGOIN  0
#define P_EGOH1  2048
#define P_ADOIN  24576
#define P_EGOH2  40960
#define P_PROJIN 40960
#define P_H1     49152
#define P_OBSRAW 49152
#define P_OUT    73728
#define POOL_BYTES 77824   // 76KB -> 2 blocks/CU (152KB of 160KB)

// C(out 16R rows x 32 cols/wave) = act(A @ WT^T + bias). Column-split:
// wave w owns cols w*32 + c2*16 + lr. Each B fragment read once per block.
template<int KP, int R, bool ACT>
__device__ __forceinline__ void gemm_block(const __bf16* __restrict__ sA, int aRow0,
                                           __bf16* __restrict__ sC, int cRow0,
                                           const __bf16* __restrict__ WT,
                                           const float* __restrict__ bias,
                                           int w, int lr, int lg)
{
  constexpr int NKB = KP / 32;
  f32x4 acc[R][2];
  #pragma unroll
  for (int t = 0; t < R; ++t) {
    acc[t][0] = f32x4{0.f,0.f,0.f,0.f};
    acc[t][1] = f32x4{0.f,0.f,0.f,0.f};
  }
  #pragma unroll
  for (int kb = 0; kb < NKB; ++kb) {
    bf16x8 af[R];
    #pragma unroll
    for (int t = 0; t < R; ++t)
      af[t] = lds_loadA(sA, aRow0 + t*16 + lr, kb*64 + lg*16, KP*2);
    #pragma unroll
    for (int c2 = 0; c2 < 2; ++c2) {
      const int col = w*32 + c2*16 + lr;
      bf16x8 bfr = *reinterpret_cast<const bf16x8*>(WT + col*KP + kb*32 + lg*8);
      #pragma unroll
      for (int t = 0; t < R; ++t)
        acc[t][c2] = __builtin_amdgcn_mfma_f32_16x16x32_bf16(af[t], bfr, acc[t][c2], 0, 0, 0);
    }
  }
  #pragma unroll
  for (int c2 = 0; c2 < 2; ++c2) {
    const int col = w*32 + c2*16 + lr;
    const float bv = bias[col];
    #pragma unroll
    for (int t = 0; t < R; ++t) {
      #pragma unroll
      for (int e = 0; e < 4; ++e) {
        float x = acc[t][c2][e] + bv;
        if (ACT) x = x > 0.f ? x : 0.01f * x;
        lds_store_bf16(sC, cRow0 + t*16 + lg*4 + e, col, (__bf16)x);
      }
    }
  }
}

__global__ __launch_bounds__(512, 4) void fused_kernel(
    const float* __restrict__ obs,
    const float* __restrict__ eb0, const float* __restrict__ eb1,
    const float* __restrict__ ab0, const float* __restrict__ ab1,
    const float* __restrict__ latb, const float* __restrict__ projb,
    const __bf16* __restrict__ ws,
    float* __restrict__ out)
{
  const int tid = threadIdx.x;
  const int w  = tid >> 6;   // 8 waves
  const int l  = tid & 63;
  const int lr = l & 15;
  const int lg = l >> 4;
  const int b0 = blockIdx.x * 16;

  __shared__ __align__(16) char pool[POOL_BYTES];
  __bf16* sEgoIn = reinterpret_cast<__bf16*>(pool + P_EGOIN);
  __bf16* sEgoH1 = reinterpret_cast<__bf16*>(pool + P_EGOH1);
  __bf16* sAdoIn = reinterpret_cast<__bf16*>(pool + P_ADOIN);
  __bf16* sEgoH2 = reinterpret_cast<__bf16*>(pool + P_EGOH2);
  __bf16* sProj  = reinterpret_cast<__bf16*>(pool + P_PROJIN);
  __bf16* sAdo2  = reinterpret_cast<__bf16*>(pool + P_ADO2);
  __bf16* sH1    = reinterpret_cast<__bf16*>(pool + P_H1);
  float*  sObsF  = reinterpret_cast<float*>(pool + P_OBSRAW);
  float*  sLogF  = reinterpret_cast<float*>(pool + P_OUT);
  float*  sOutF  = reinterpret_cast<float*>(pool + P_OUT);

  // ---- phase 1a: coalesced obs -> LDS (fp32) + NT fp32 passthrough out[:, :48]
  {
    const f32x4* o4 = reinterpret_cast<const f32x4*>(obs);
    #pragma unroll
    for (int idx = tid; idx < 672; idx += 512) {   // 16 rows x 42 f32x4
      int row = idx / 42, c4 = idx % 42;
      f32x4 v = o4[(size_t)(b0+row)*42 + c4];
      *reinterpret_cast<f32x4*>(sObsF + row*168 + c4*4) = v;
      if (c4 < 12)
        __builtin_nontemporal_store(v,
            reinterpret_cast<f32x4*>(out + (size_t)(b0+row)*112 + c4*4));
    }
  }
  __syncthreads();

  // ---- phase 1b: build bf16 inputs from LDS fp32
  {
    if (tid < 192) {            // ego: 16 rows x 12 f32x4
      int row = tid / 12, c4 = tid % 12;
      f32x4 v = *reinterpret_cast<const f32x4*>(sObsF + row*168 + c4*4);
      bf16x4 bv = { (__bf16)v[0], (__bf16)v[1], (__bf16)v[2], (__bf16)v[3] };
      int off = (row*128 + c4*8) ^ ((row&7)<<4);
      *reinterpret_cast<bf16x4*>(reinterpret_cast<char*>(sEgoIn) + off) = bv;
    } else if (tid < 256) {     // ego zero pad cols 48..63
      int t = tid - 192;
      int row = t >> 2, ch = t & 3;
      bf16x4 z = {};
      int off = (row*128 + 96 + ch*8) ^ ((row&7)<<4);
      *reinterpret_cast<bf16x4*>(reinterpret_cast<char*>(sEgoIn) + off) = z;
    }
    if (tid >= 256 && tid < 496) {  // ado gather: 80 lds rows x 3 chunks of 8
      int t = tid - 256;
      int ldsrow = t / 3, p = t % 3;
      int n = ldsrow >> 4, r = ldsrow & 15;
      const float* orow = sObsF + r*168 + 48;
      bf16x8 v;
      #pragma unroll
      for (int j = 0; j < 8; ++j) v[j] = (__bf16)orow[(p*8+j)*5 + n];
      int off = (ldsrow*64 + p*16) ^ ((ldsrow&7)<<4);
      *reinterpret_cast<bf16x8*>(reinterpret_cast<char*>(sAdoIn) + off) = v;
    }
    if (tid >= 432) {               // cols 24..31: teamid + zero pad
      int t = tid - 432;            // 0..79
      int n = t >> 4;
      bf16x8 v = {};
      v[0] = (__bf16)((n >= 2) ? 1.0f : 0.0f);   // team_ids[1:6] = 0,0,1,1,1
      int off = (t*64 + 48) ^ ((t&7)<<4);
      *reinterpret_cast<bf16x8*>(reinterpret_cast<char*>(sAdoIn) + off) = v;
    }
  }
  __syncthreads();

  // ---- phase 2: ego0 + ado0 (agents 0..2 -> sH1 rows 0..47)
  gemm_block<64, 1, true>(sEgoIn, 0, sEgoH1, 0, ws + OFF_EGO0, eb0, w, lr, lg);
  gemm_block<32, 3, true>(sAdoIn, 0, sH1,    0, ws + OFF_ADO0, ab0, w, lr, lg);
  __syncthreads();

  // ---- phase 3: ego1
  gemm_block<256, 1, true>(sEgoH1, 0, sEgoH2, 0, ws + OFF_EGO1, eb1, w, lr, lg);
  __syncthreads();

  // ---- phase 4: sel (regs, 1/8 folded) + ado1 agents 0..2 -> sAdo2 rows 0..47
  f32x4 slct[2];
  {
    const __bf16* WT = ws + OFF_SEL;
    slct[0] = f32x4{0.f,0.f,0.f,0.f};
    slct[1] = f32x4{0.f,0.f,0.f,0.f};
    #pragma unroll
    for (int kb = 0; kb < 8; ++kb) {
      bf16x8 af = lds_loadA(sEgoH2, lr, kb*64 + lg*16, 512);
      #pragma unroll
      for (int c2 = 0; c2 < 2; ++c2) {
        bf16x8 bfr = *reinterpret_cast<const bf16x8*>(WT + (w*32+c2*16+lr)*256 + kb*32 + lg*8);
        slct[c2] = __builtin_amdgcn_mfma_f32_16x16x32_bf16(af, bfr, slct[c2], 0, 0, 0);
      }
    }
    slct[0] *= 0.125f;   // fold 1/sqrt(AD) into slct
    slct[1] *= 0.125f;
  }
  gemm_block<256, 3, true>(sH1, 0, sAdo2, 0, ws + OFF_ADO1, ab1, w, lr, lg);
  __syncthreads();

  // ---- phase 5: ado0 agents 3..4 -> sH1 rows 0..31
  gemm_block<32, 2, true>(sAdoIn, 48, sH1, 0, ws + OFF_ADO0, ab0, w, lr, lg);
  __syncthreads();

  // ---- phase 6: ado1 agents 3..4 -> sAdo2 rows 48..79
  gemm_block<256, 2, true>(sH1, 0, sAdo2, 48, ws + OFF_ADO1, ab1, w, lr, lg);
  __syncthreads();

  // ---- phase 7: key pass -> pair-wise logit exchange -> softmax -> lat pass
  f32x4 part[5];
  #pragma unroll
  for (int n = 0; n < 5; ++n) part[n] = f32x4{0.f,0.f,0.f,0.f};
  {
    const __bf16* WK = ws + OFF_KEY;
    #pragma unroll
    for (int c2 = 0; c2 < 2; ++c2) {
      f32x4 kacc[5];
      #pragma unroll
      for (int n = 0; n < 5; ++n) kacc[n] = f32x4{0.f,0.f,0.f,0.f};
      const int col = w*32 + c2*16 + lr;
      #pragma unroll
      for (int kb = 0; kb < 8; ++kb) {
        bf16x8 af[5];
        #pragma unroll
        for (int n = 0; n < 5; ++n)
          af[n] = lds_loadA(sAdo2, n*16 + lr, kb*64 + lg*16, 512);
        bf16x8 bk = *reinterpret_cast<const bf16x8*>(WK + col*256 + kb*32 + lg*8);
        #pragma unroll
        for (int n = 0; n < 5; ++n)
          kacc[n] = __builtin_amdgcn_mfma_f32_16x16x32_bf16(af[n], bk, kacc[n], 0, 0, 0);
      }
      #pragma unroll
      for (int n = 0; n < 5; ++n) part[n] += kacc[n] * slct[c2];
    }
  }
  // reduce over lr lanes (sum over this wave's 32 d-dims)
  #pragma unroll
  for (int n = 0; n < 5; ++n) {
    #pragma unroll
    for (int m = 1; m < 16; m <<= 1) {
      part[n][0] += __shfl_xor(part[n][0], m);
      part[n][1] += __shfl_xor(part[n][1], m);
      part[n][2] += __shfl_xor(part[n][2], m);
      part[n][3] += __shfl_xor(part[n][3], m);
    }
  }
  // publish wave partials: sLogF[w][n][row] (f32x4 per (w,n,lg))
  #pragma unroll
  for (int n = 0; n < 5; ++n)
    if (lr == n)
      *reinterpret_cast<f32x4*>(sLogF + (w*5 + n)*16 + lg*4) = part[n];
  __syncthreads();
  // full logits = this wave's partial + partner wave's partial; exact softmax
  f32x4 p[5];
  {
    f32x4 lt[5];
    #pragma unroll
    for (int n = 0; n < 5; ++n)
      lt[n] = *reinterpret_cast<const f32x4*>(sLogF + (w*5 + n)*16 + lg*4)
            + *reinterpret_cast<const f32x4*>(sLogF + ((w^1)*5 + n)*16 + lg*4);
    f32x4 mx = lt[0];
    #pragma unroll
    for (int n = 1; n < 5; ++n)
      #pragma unroll
      for (int e = 0; e < 4; ++e) mx[e] = fmaxf(mx[e], lt[n][e]);
    f32x4 s = f32x4{0.f,0.f,0.f,0.f};
    #pragma unroll
    for (int n = 0; n < 5; ++n) {
      #pragma unroll
      for (int e = 0; e < 4; ++e) p[n][e] = __expf(lt[n][e] - mx[e]);
      s += p[n];
    }
    f32x4 inv;
    #pragma unroll
    for (int e = 0; e < 4; ++e) inv[e] = 1.0f / s[e];
    #pragma unroll
    for (int n = 0; n < 5; ++n) p[n] *= inv;
  }
  // lat pass: weighted aggregation in registers
  f32x4 agg[2];
  agg[0] = f32x4{0.f,0.f,0.f,0.f};
  agg[1] = f32x4{0.f,0.f,0.f,0.f};
  {
    const __bf16* WL = ws + OFF_LAT;
    #pragma unroll
    for (int c2 = 0; c2 < 2; ++c2) {
      f32x4 lacc[5];
      #pragma unroll
      for (int n = 0; n < 5; ++n) lacc[n] = f32x4{0.f,0.f,0.f,0.f};
      const int col = w*32 + c2*16 + lr;
      #pragma unroll
      for (int kb = 0; kb < 8; ++kb) {
        bf16x8 af[5];
        #pragma unroll
        for (int n = 0; n < 5; ++n)
          af[n] = lds_loadA(sAdo2, n*16 + lr, kb*64 + lg*16, 512);
        bf16x8 bl = *reinterpret_cast<const bf16x8*>(WL + col*256 + kb*32 + lg*8);
        #pragma unroll
        for (int n = 0; n < 5; ++n)
          lacc[n] = __builtin_amdgcn_mfma_f32_16x16x32_bf16(af[n], bl, lacc[n], 0, 0, 0);
      }
      const float lb = latb[col];
      #pragma unroll
      for (int n = 0; n < 5; ++n) {
        #pragma unroll
        for (int e = 0; e < 4; ++e) {
          float x = lacc[n][e] + lb;
          x = x > 0.f ? x : 0.01f * x;
          agg[c2][e] += p[n][e] * x;
        }
      }
    }
  }
  // agg -> sProj (proj input, bf16 swz). Overwrites sEgoH2 (dead).
  #pragma unroll
  for (int c2 = 0; c2 < 2; ++c2)
    #pragma unroll
    for (int e = 0; e < 4; ++e)
      lds_store_bf16(sProj, lg*4 + e, w*32 + c2*16 + lr, (__bf16)agg[c2][e]);
  __syncthreads();

  // ---- phase 8: proj (16x256)@(256x64); waves 0..3 -> cols w*16..w*16+15
  if (w < 4) {
    const __bf16* WT = ws + OFF_PROJ;
    f32x4 pacc = f32x4{0.f,0.f,0.f,0.f};
    #pragma unroll
    for (int kb = 0; kb < 8; ++kb) {
      bf16x8 af = lds_loadA(sProj, lr, kb*64 + lg*16, 512);
      bf16x8 bfr = *reinterpret_cast<const bf16x8*>(WT + (w*16+lr)*256 + kb*32 + lg*8);
      pacc = __builtin_amdgcn_mfma_f32_16x16x32_bf16(af, bfr, pacc, 0, 0, 0);
    }
    const float pb = projb[w*16 + lr];
    #pragma unroll
    for (int e = 0; e < 4; ++e)
      sOutF[(lg*4 + e)*64 + w*16 + lr] = pacc[e] + pb;
  }
  __syncthreads();

  // ---- phase 9: coalesced NT float4 writes of out[:, 48:112]
  if (tid < 256) {
    int row = tid >> 4, q = tid & 15;
    f32x4 v = *reinterpret_cast<const f32x4*>(sOutF + row*64 + q*4);
    __builtin_nontemporal_store(v,
        reinterpret_cast<f32x4*>(out + (size_t)(b0+row)*112 + 48 + q*4));
  }
}

extern "C" void kernel_launch(void* const* d_in, const int* in_sizes, int n_in,
                              void* d_out, int out_size, void* d_ws, size_t ws_size,
                              hipStream_t stream) {
  const float* obs   = (const float*)d_in[0];
  const float* ew0   = (const float*)d_in[1];
  const float* eb0   = (const float*)d_in[2];
  const float* ew1   = (const float*)d_in[3];
  const float* eb1   = (const float*)d_in[4];
  const float* aw0   = (const float*)d_in[5];
  const float* ab0   = (const float*)d_in[6];
  const float* aw1   = (const float*)d_in[7];
  const float* ab1   = (const float*)d_in[8];
  const float* keyw  = (const float*)d_in[9];
  const float* selw  = (const float*)d_in[10];
  const float* latw  = (const float*)d_in[11];
  const float* latb  = (const float*)d_in[12];
  const float* projw = (const float*)d_in[13];
  const float* projb = (const float*)d_in[14];
  __bf16* ws = (__bf16*)d_ws;
  float* out = (float*)d_out;

  prep_weights<<<dim3((WS_ELEMS + 255)/256), dim3(256), 0, stream>>>(
      ew0, ew1, aw0, aw1, keyw, selw, latw, projw, ws);
  fused_kernel<<<dim3(65536/16), dim3(512), 0, stream>>>(
      obs, eb0, eb1, ab0, ab1, latb, projb, ws, out);
}

// Round 3
// 457.660 us; speedup vs baseline: 4.0744x; 1.0001x over previous
//
#include <hip/hip_runtime.h>
#include <hip/hip_bf16.h>

// EncoderAttention4 v4: v3 + pinned waves_per_eu(4,4) to kill the VGPR=64 clamp.
// B=65536, NEGO=48, NADO=24, NADOAG=5, E=256, H=4, AD=64. Out: (B,112) fp32.
//
// v3 post-mortem: __launch_bounds__(512,4) let the backend target 8 waves/EU
// and clamp VGPRs to 64, but LDS (76KB -> 2 blocks/CU) caps occupancy at
// 4 waves/EU anyway. Phase-7 live state (~85 f32 regs) can't fit in 64 ->
// spills + LDS reloads serialized the MFMA loops (MfmaUtil stuck at 13%,
// bank conflicts doubled). Fix: amdgpu_waves_per_eu(4,4) pins the register
// budget at 128 VGPRs, which fits all phases without spilling.

typedef __bf16 bf16x8 __attribute__((ext_vector_type(8)));
typedef __bf16 bf16x4 __attribute__((ext_vector_type(4)));
typedef float  f32x4  __attribute__((ext_vector_type(4)));

// Workspace layout (bf16 elements), unchanged.
#define OFF_EGO0 0        // [256][64]  (K=48 padded to 64)
#define OFF_EGO1 16384    // [256][256]
#define OFF_ADO0 81920    // [256][32]  (K=25 padded to 32)
#define OFF_ADO1 90112    // [256][256]
#define OFF_SEL  155648   // [256][256] col c -> head c>>6, d c&63
#define OFF_KEY  221184
#define OFF_LAT  286720
#define OFF_PROJ 352256   // [64][256]
#define WS_ELEMS 368640

__global__ __launch_bounds__(256) void prep_weights(
    const float* __restrict__ ew0, const float* __restrict__ ew1,
    const float* __restrict__ aw0, const float* __restrict__ aw1,
    const float* __restrict__ keyw, const float* __restrict__ selw,
    const float* __restrict__ latw, const float* __restrict__ projw,
    __bf16* __restrict__ ws)
{
  int i = blockIdx.x * 256 + threadIdx.x;
  if (i >= WS_ELEMS) return;
  float v;
  if (i < OFF_EGO1)      { int j=i;          int c=j>>6, k=j&63;  v = (k<48) ? ew0[k*256+c] : 0.f; }
  else if (i < OFF_ADO0) { int j=i-OFF_EGO1; int c=j>>8, k=j&255; v = ew1[k*256+c]; }
  else if (i < OFF_ADO1) { int j=i-OFF_ADO0; int c=j>>5, k=j&31;  v = (k<25) ? aw0[k*256+c] : 0.f; }
  else if (i < OFF_SEL)  { int j=i-OFF_ADO1; int c=j>>8, k=j&255; v = aw1[k*256+c]; }
  else if (i < OFF_KEY)  { int j=i-OFF_SEL;  int c=j>>8, k=j&255; v = selw[(c>>6)*16384 + k*64 + (c&63)]; }
  else if (i < OFF_LAT)  { int j=i-OFF_KEY;  int c=j>>8, k=j&255; v = keyw[(c>>6)*16384 + k*64 + (c&63)]; }
  else if (i < OFF_PROJ) { int j=i-OFF_LAT;  int c=j>>8, k=j&255; v = latw[(c>>6)*16384 + k*64 + (c&63)]; }
  else                   { int j=i-OFF_PROJ; int c=j>>8, k=j&255; v = projw[k*64+c]; }
  ws[i] = (__bf16)v;
}

// XOR-swizzled LDS accessors. byte ^= (row&7)<<4.
__device__ __forceinline__ bf16x8 lds_loadA(const __bf16* base, int row, int kByte, int rowBytes) {
  int off = (row * rowBytes + kByte) ^ ((row & 7) << 4);
  return *reinterpret_cast<const bf16x8*>(reinterpret_cast<const char*>(base) + off);
}
__device__ __forceinline__ void lds_store_bf16(__bf16* base, int row, int col, __bf16 v) {
  int off = (row * 512 + col * 2) ^ ((row & 7) << 4);  // 256-col tiles only
  *reinterpret_cast<__bf16*>(reinterpret_cast<char*>(base) + off) = v;
}

// LDS pool (bytes). Aliased regions with phase-disjoint lifetimes:
//   P_ADO2  [0,40960)      : ado activations, 80x512 swz (written ph4/ph6)
//     P_EGOIN [0,2048)     : ego input 16x128 swz   (dead after ph2)
//     P_EGOH1 [2048,10240) : ego hidden1 16x512 swz (dead after ph3)
//     P_ADOIN [24576,29696): ado input 80x64 swz    (dead after ph5)
//   P_EGOH2 [40960,49152)  : ego hidden2 16x512 swz (dead after ph4 'sel')
//     P_PROJIN (same addr) : proj input 16x512 swz  (written ph7)
//   P_H1    [49152,73728)  : ado hidden1 half, 48x512 swz (dead after ph6)
//     P_OBSRAW (same addr) : raw fp32 obs 16x168    (dead after ph1b)
//   P_OUT   [73728,77824)  : logit exchange (ph7) then proj fp32 out (ph8)
#define P_ADO2   0
#define P_EGOIN  0
#define P_EGOH1  2048
#define P_ADOIN  24576
#define P_EGOH2  40960
#define P_PROJIN 40960
#define P_H1     49152
#define P_OBSRAW 49152
#define P_OUT    73728
#define POOL_BYTES 77824   // 76KB -> 2 blocks/CU (152KB of 160KB)

// C(out 16R rows x 32 cols/wave) = act(A @ WT^T + bias). Column-split:
// wave w owns cols w*32 + c2*16 + lr. Each B fragment read once per block.
template<int KP, int R, bool ACT>
__device__ __forceinline__ void gemm_block(const __bf16* __restrict__ sA, int aRow0,
                                           __bf16* __restrict__ sC, int cRow0,
                                           const __bf16* __restrict__ WT,
                                           const float* __restrict__ bias,
                                           int w, int lr, int lg)
{
  constexpr int NKB = KP / 32;
  f32x4 acc[R][2];
  #pragma unroll
  for (int t = 0; t < R; ++t) {
    acc[t][0] = f32x4{0.f,0.f,0.f,0.f};
    acc[t][1] = f32x4{0.f,0.f,0.f,0.f};
  }
  #pragma unroll
  for (int kb = 0; kb < NKB; ++kb) {
    bf16x8 af[R];
    #pragma unroll
    for (int t = 0; t < R; ++t)
      af[t] = lds_loadA(sA, aRow0 + t*16 + lr, kb*64 + lg*16, KP*2);
    #pragma unroll
    for (int c2 = 0; c2 < 2; ++c2) {
      const int col = w*32 + c2*16 + lr;
      bf16x8 bfr = *reinterpret_cast<const bf16x8*>(WT + col*KP + kb*32 + lg*8);
      #pragma unroll
      for (int t = 0; t < R; ++t)
        acc[t][c2] = __builtin_amdgcn_mfma_f32_16x16x32_bf16(af[t], bfr, acc[t][c2], 0, 0, 0);
    }
  }
  #pragma unroll
  for (int c2 = 0; c2 < 2; ++c2) {
    const int col = w*32 + c2*16 + lr;
    const float bv = bias[col];
    #pragma unroll
    for (int t = 0; t < R; ++t) {
      #pragma unroll
      for (int e = 0; e < 4; ++e) {
        float x = acc[t][c2][e] + bv;
        if (ACT) x = x > 0.f ? x : 0.01f * x;
        lds_store_bf16(sC, cRow0 + t*16 + lg*4 + e, col, (__bf16)x);
      }
    }
  }
}

__global__ __launch_bounds__(512)
__attribute__((amdgpu_waves_per_eu(4, 4)))
void fused_kernel(
    const float* __restrict__ obs,
    const float* __restrict__ eb0, const float* __restrict__ eb1,
    const float* __restrict__ ab0, const float* __restrict__ ab1,
    const float* __restrict__ latb, const float* __restrict__ projb,
    const __bf16* __restrict__ ws,
    float* __restrict__ out)
{
  const int tid = threadIdx.x;
  const int w  = tid >> 6;   // 8 waves
  const int l  = tid & 63;
  const int lr = l & 15;
  const int lg = l >> 4;
  const int b0 = blockIdx.x * 16;

  __shared__ __align__(16) char pool[POOL_BYTES];
  __bf16* sEgoIn = reinterpret_cast<__bf16*>(pool + P_EGOIN);
  __bf16* sEgoH1 = reinterpret_cast<__bf16*>(pool + P_EGOH1);
  __bf16* sAdoIn = reinterpret_cast<__bf16*>(pool + P_ADOIN);
  __bf16* sEgoH2 = reinterpret_cast<__bf16*>(pool + P_EGOH2);
  __bf16* sProj  = reinterpret_cast<__bf16*>(pool + P_PROJIN);
  __bf16* sAdo2  = reinterpret_cast<__bf16*>(pool + P_ADO2);
  __bf16* sH1    = reinterpret_cast<__bf16*>(pool + P_H1);
  float*  sObsF  = reinterpret_cast<float*>(pool + P_OBSRAW);
  float*  sLogF  = reinterpret_cast<float*>(pool + P_OUT);
  float*  sOutF  = reinterpret_cast<float*>(pool + P_OUT);

  // ---- phase 1a: coalesced obs -> LDS (fp32) + NT fp32 passthrough out[:, :48]
  {
    const f32x4* o4 = reinterpret_cast<const f32x4*>(obs);
    #pragma unroll
    for (int idx = tid; idx < 672; idx += 512) {   // 16 rows x 42 f32x4
      int row = idx / 42, c4 = idx % 42;
      f32x4 v = o4[(size_t)(b0+row)*42 + c4];
      *reinterpret_cast<f32x4*>(sObsF + row*168 + c4*4) = v;
      if (c4 < 12)
        __builtin_nontemporal_store(v,
            reinterpret_cast<f32x4*>(out + (size_t)(b0+row)*112 + c4*4));
    }
  }
  __syncthreads();

  // ---- phase 1b: build bf16 inputs from LDS fp32
  {
    if (tid < 192) {            // ego: 16 rows x 12 f32x4
      int row = tid / 12, c4 = tid % 12;
      f32x4 v = *reinterpret_cast<const f32x4*>(sObsF + row*168 + c4*4);
      bf16x4 bv = { (__bf16)v[0], (__bf16)v[1], (__bf16)v[2], (__bf16)v[3] };
      int off = (row*128 + c4*8) ^ ((row&7)<<4);
      *reinterpret_cast<bf16x4*>(reinterpret_cast<char*>(sEgoIn) + off) = bv;
    } else if (tid < 256) {     // ego zero pad cols 48..63
      int t = tid - 192;
      int row = t >> 2, ch = t & 3;
      bf16x4 z = {};
      int off = (row*128 + 96 + ch*8) ^ ((row&7)<<4);
      *reinterpret_cast<bf16x4*>(reinterpret_cast<char*>(sEgoIn) + off) = z;
    }
    if (tid >= 256 && tid < 496) {  // ado gather: 80 lds rows x 3 chunks of 8
      int t = tid - 256;
      int ldsrow = t / 3, p = t % 3;
      int n = ldsrow >> 4, r = ldsrow & 15;
      const float* orow = sObsF + r*168 + 48;
      bf16x8 v;
      #pragma unroll
      for (int j = 0; j < 8; ++j) v[j] = (__bf16)orow[(p*8+j)*5 + n];
      int off = (ldsrow*64 + p*16) ^ ((ldsrow&7)<<4);
      *reinterpret_cast<bf16x8*>(reinterpret_cast<char*>(sAdoIn) + off) = v;
    }
    if (tid >= 432) {               // cols 24..31: teamid + zero pad
      int t = tid - 432;            // 0..79
      int n = t >> 4;
      bf16x8 v = {};
      v[0] = (__bf16)((n >= 2) ? 1.0f : 0.0f);   // team_ids[1:6] = 0,0,1,1,1
      int off = (t*64 + 48) ^ ((t&7)<<4);
      *reinterpret_cast<bf16x8*>(reinterpret_cast<char*>(sAdoIn) + off) = v;
    }
  }
  __syncthreads();

  // ---- phase 2: ego0 + ado0 (agents 0..2 -> sH1 rows 0..47)
  gemm_block<64, 1, true>(sEgoIn, 0, sEgoH1, 0, ws + OFF_EGO0, eb0, w, lr, lg);
  gemm_block<32, 3, true>(sAdoIn, 0, sH1,    0, ws + OFF_ADO0, ab0, w, lr, lg);
  __syncthreads();

  // ---- phase 3: ego1
  gemm_block<256, 1, true>(sEgoH1, 0, sEgoH2, 0, ws + OFF_EGO1, eb1, w, lr, lg);
  __syncthreads();

  // ---- phase 4: sel (regs, 1/8 folded) + ado1 agents 0..2 -> sAdo2 rows 0..47
  f32x4 slct[2];
  {
    const __bf16* WT = ws + OFF_SEL;
    slct[0] = f32x4{0.f,0.f,0.f,0.f};
    slct[1] = f32x4{0.f,0.f,0.f,0.f};
    #pragma unroll
    for (int kb = 0; kb < 8; ++kb) {
      bf16x8 af = lds_loadA(sEgoH2, lr, kb*64 + lg*16, 512);
      #pragma unroll
      for (int c2 = 0; c2 < 2; ++c2) {
        bf16x8 bfr = *reinterpret_cast<const bf16x8*>(WT + (w*32+c2*16+lr)*256 + kb*32 + lg*8);
        slct[c2] = __builtin_amdgcn_mfma_f32_16x16x32_bf16(af, bfr, slct[c2], 0, 0, 0);
      }
    }
    slct[0] *= 0.125f;   // fold 1/sqrt(AD) into slct
    slct[1] *= 0.125f;
  }
  gemm_block<256, 3, true>(sH1, 0, sAdo2, 0, ws + OFF_ADO1, ab1, w, lr, lg);
  __syncthreads();

  // ---- phase 5: ado0 agents 3..4 -> sH1 rows 0..31
  gemm_block<32, 2, true>(sAdoIn, 48, sH1, 0, ws + OFF_ADO0, ab0, w, lr, lg);
  __syncthreads();

  // ---- phase 6: ado1 agents 3..4 -> sAdo2 rows 48..79
  gemm_block<256, 2, true>(sH1, 0, sAdo2, 48, ws + OFF_ADO1, ab1, w, lr, lg);
  __syncthreads();

  // ---- phase 7: key pass -> pair-wise logit exchange -> softmax -> lat pass
  f32x4 part[5];
  #pragma unroll
  for (int n = 0; n < 5; ++n) part[n] = f32x4{0.f,0.f,0.f,0.f};
  {
    const __bf16* WK = ws + OFF_KEY;
    #pragma unroll
    for (int c2 = 0; c2 < 2; ++c2) {
      f32x4 kacc[5];
      #pragma unroll
      for (int n = 0; n < 5; ++n) kacc[n] = f32x4{0.f,0.f,0.f,0.f};
      const int col = w*32 + c2*16 + lr;
      #pragma unroll
      for (int kb = 0; kb < 8; ++kb) {
        bf16x8 af[5];
        #pragma unroll
        for (int n = 0; n < 5; ++n)
          af[n] = lds_loadA(sAdo2, n*16 + lr, kb*64 + lg*16, 512);
        bf16x8 bk = *reinterpret_cast<const bf16x8*>(WK + col*256 + kb*32 + lg*8);
        #pragma unroll
        for (int n = 0; n < 5; ++n)
          kacc[n] = __builtin_amdgcn_mfma_f32_16x16x32_bf16(af[n], bk, kacc[n], 0, 0, 0);
      }
      #pragma unroll
      for (int n = 0; n < 5; ++n) part[n] += kacc[n] * slct[c2];
    }
  }
  // reduce over lr lanes (sum over this wave's 32 d-dims)
  #pragma unroll
  for (int n = 0; n < 5; ++n) {
    #pragma unroll
    for (int m = 1; m < 16; m <<= 1) {
      part[n][0] += __shfl_xor(part[n][0], m);
      part[n][1] += __shfl_xor(part[n][1], m);
      part[n][2] += __shfl_xor(part[n][2], m);
      part[n][3] += __shfl_xor(part[n][3], m);
    }
  }
  // publish wave partials: sLogF[w][n][row] (f32x4 per (w,n,lg))
  #pragma unroll
  for (int n = 0; n < 5; ++n)
    if (lr == n)
      *reinterpret_cast<f32x4*>(sLogF + (w*5 + n)*16 + lg*4) = part[n];
  __syncthreads();
  // full logits = this wave's partial + partner wave's partial; exact softmax
  f32x4 p[5];
  {
    f32x4 lt[5];
    #pragma unroll
    for (int n = 0; n < 5; ++n)
      lt[n] = *reinterpret_cast<const f32x4*>(sLogF + (w*5 + n)*16 + lg*4)
            + *reinterpret_cast<const f32x4*>(sLogF + ((w^1)*5 + n)*16 + lg*4);
    f32x4 mx = lt[0];
    #pragma unroll
    for (int n = 1; n < 5; ++n)
      #pragma unroll
      for (int e = 0; e < 4; ++e) mx[e] = fmaxf(mx[e], lt[n][e]);
    f32x4 s = f32x4{0.f,0.f,0.f,0.f};
    #pragma unroll
    for (int n = 0; n < 5; ++n) {
      #pragma unroll
      for (int e = 0; e < 4; ++e) p[n][e] = __expf(lt[n][e] - mx[e]);
      s += p[n];
    }
    f32x4 inv;
    #pragma unroll
    for (int e = 0; e < 4; ++e) inv[e] = 1.0f / s[e];
    #pragma unroll
    for (int n = 0; n < 5; ++n) p[n] *= inv;
  }
  // lat pass: weighted aggregation in registers
  f32x4 agg[2];
  agg[0] = f32x4{0.f,0.f,0.f,0.f};
  agg[1] = f32x4{0.f,0.f,0.f,0.f};
  {
    const __bf16* WL = ws + OFF_LAT;
    #pragma unroll
    for (int c2 = 0; c2 < 2; ++c2) {
      f32x4 lacc[5];
      #pragma unroll
      for (int n = 0; n < 5; ++n) lacc[n] = f32x4{0.f,0.f,0.f,0.f};
      const int col = w*32 + c2*16 + lr;
      #pragma unroll
      for (int kb = 0; kb < 8; ++kb) {
        bf16x8 af[5];
        #pragma unroll
        for (int n = 0; n < 5; ++n)
          af[n] = lds_loadA(sAdo2, n*16 + lr, kb*64 + lg*16, 512);
        bf16x8 bl = *reinterpret_cast<const bf16x8*>(WL + col*256 + kb*32 + lg*8);
        #pragma unroll
        for (int n = 0; n < 5; ++n)
          lacc[n] = __builtin_amdgcn_mfma_f32_16x16x32_bf16(af[n], bl, lacc[n], 0, 0, 0);
      }
      const float lb = latb[col];
      #pragma unroll
      for (int n = 0; n < 5; ++n) {
        #pragma unroll
        for (int e = 0; e < 4; ++e) {
          float x = lacc[n][e] + lb;
          x = x > 0.f ? x : 0.01f * x;
          agg[c2][e] += p[n][e] * x;
        }
      }
    }
  }
  // agg -> sProj (proj input, bf16 swz). Overwrites sEgoH2 (dead).
  #pragma unroll
  for (int c2 = 0; c2 < 2; ++c2)
    #pragma unroll
    for (int e = 0; e < 4; ++e)
      lds_store_bf16(sProj, lg*4 + e, w*32 + c2*16 + lr, (__bf16)agg[c2][e]);
  __syncthreads();

  // ---- phase 8: proj (16x256)@(256x64); waves 0..3 -> cols w*16..w*16+15
  if (w < 4) {
    const __bf16* WT = ws + OFF_PROJ;
    f32x4 pacc = f32x4{0.f,0.f,0.f,0.f};
    #pragma unroll
    for (int kb = 0; kb < 8; ++kb) {
      bf16x8 af = lds_loadA(sProj, lr, kb*64 + lg*16, 512);
      bf16x8 bfr = *reinterpret_cast<const bf16x8*>(WT + (w*16+lr)*256 + kb*32 + lg*8);
      pacc = __builtin_amdgcn_mfma_f32_16x16x32_bf16(af, bfr, pacc, 0, 0, 0);
    }
    const float pb = projb[w*16 + lr];
    #pragma unroll
    for (int e = 0; e < 4; ++e)
      sOutF[(lg*4 + e)*64 + w*16 + lr] = pacc[e] + pb;
  }
  __syncthreads();

  // ---- phase 9: coalesced NT float4 writes of out[:, 48:112]
  if (tid < 256) {
    int row = tid >> 4, q = tid & 15;
    f32x4 v = *reinterpret_cast<const f32x4*>(sOutF + row*64 + q*4);
    __builtin_nontemporal_store(v,
        reinterpret_cast<f32x4*>(out + (size_t)(b0+row)*112 + 48 + q*4));
  }
}

extern "C" void kernel_launch(void* const* d_in, const int* in_sizes, int n_in,
                              void* d_out, int out_size, void* d_ws, size_t ws_size,
                              hipStream_t stream) {
  const float* obs   = (const float*)d_in[0];
  const float* ew0   = (const float*)d_in[1];
  const float* eb0   = (const float*)d_in[2];
  const float* ew1   = (const float*)d_in[3];
  const float* eb1   = (const float*)d_in[4];
  const float* aw0   = (const float*)d_in[5];
  const float* ab0   = (const float*)d_in[6];
  const float* aw1   = (const float*)d_in[7];
  const float* ab1   = (const float*)d_in[8];
  const float* keyw  = (const float*)d_in[9];
  const float* selw  = (const float*)d_in[10];
  const float* latw  = (const float*)d_in[11];
  const float* latb  = (const float*)d_in[12];
  const float* projw = (const float*)d_in[13];
  const float* projb = (const float*)d_in[14];
  __bf16* ws = (__bf16*)d_ws;
  float* out = (float*)d_out;

  prep_weights<<<dim3((WS_ELEMS + 255)/256), dim3(256), 0, stream>>>(
      ew0, ew1, aw0, aw1, keyw, selw, latw, projw, ws);
  fused_kernel<<<dim3(65536/16), dim3(512), 0, stream>>>(
      obs, eb0, eb1, ab0, ab1, latb, projb, ws, out);
}

// Round 4
// 449.945 us; speedup vs baseline: 4.1443x; 1.0171x over previous
//
#include <hip/hip_runtime.h>
#include <hip/hip_bf16.h>

// EncoderAttention4 v5: phase-7 rewritten kb-outer with af-hoisting.
// B=65536, NEGO=48, NADO=24, NADOAG=5, E=256, H=4, AD=64. Out: (B,112) fp32.
//
// v3/v4 post-mortem: VGPR=64 was not a backend clamp — the c2-outer phase-7
// shape only NEEDS 64 regs, so the allocator targets 8 waves/EU and cannot
// pipeline (1 outstanding L2 B-load, af[5] reloaded from LDS per c2 half:
// 160 ds_read_b128/wave in phase 7 alone, bank conflicts 2x v2). Fix: phase 7
// as two kb-outer passes (key, lat), af[5] loaded once per kb, kacc/lacc[5][2]
// accumulators -> ~85-100 live regs under a 128-reg budget (512,4), halved
// phase-7 LDS reads, and register headroom for the scheduler to keep several
// B-fragment loads in flight across kb iterations.

typedef __bf16 bf16x8 __attribute__((ext_vector_type(8)));
typedef __bf16 bf16x4 __attribute__((ext_vector_type(4)));
typedef float  f32x4  __attribute__((ext_vector_type(4)));

// Workspace layout (bf16 elements), unchanged.
#define OFF_EGO0 0        // [256][64]  (K=48 padded to 64)
#define OFF_EGO1 16384    // [256][256]
#define OFF_ADO0 81920    // [256][32]  (K=25 padded to 32)
#define OFF_ADO1 90112    // [256][256]
#define OFF_SEL  155648   // [256][256] col c -> head c>>6, d c&63
#define OFF_KEY  221184
#define OFF_LAT  286720
#define OFF_PROJ 352256   // [64][256]
#define WS_ELEMS 368640

__global__ __launch_bounds__(256) void prep_weights(
    const float* __restrict__ ew0, const float* __restrict__ ew1,
    const float* __restrict__ aw0, const float* __restrict__ aw1,
    const float* __restrict__ keyw, const float* __restrict__ selw,
    const float* __restrict__ latw, const float* __restrict__ projw,
    __bf16* __restrict__ ws)
{
  int i = blockIdx.x * 256 + threadIdx.x;
  if (i >= WS_ELEMS) return;
  float v;
  if (i < OFF_EGO1)      { int j=i;          int c=j>>6, k=j&63;  v = (k<48) ? ew0[k*256+c] : 0.f; }
  else if (i < OFF_ADO0) { int j=i-OFF_EGO1; int c=j>>8, k=j&255; v = ew1[k*256+c]; }
  else if (i < OFF_ADO1) { int j=i-OFF_ADO0; int c=j>>5, k=j&31;  v = (k<25) ? aw0[k*256+c] : 0.f; }
  else if (i < OFF_SEL)  { int j=i-OFF_ADO1; int c=j>>8, k=j&255; v = aw1[k*256+c]; }
  else if (i < OFF_KEY)  { int j=i-OFF_SEL;  int c=j>>8, k=j&255; v = selw[(c>>6)*16384 + k*64 + (c&63)]; }
  else if (i < OFF_LAT)  { int j=i-OFF_KEY;  int c=j>>8, k=j&255; v = keyw[(c>>6)*16384 + k*64 + (c&63)]; }
  else if (i < OFF_PROJ) { int j=i-OFF_LAT;  int c=j>>8, k=j&255; v = latw[(c>>6)*16384 + k*64 + (c&63)]; }
  else                   { int j=i-OFF_PROJ; int c=j>>8, k=j&255; v = projw[k*64+c]; }
  ws[i] = (__bf16)v;
}

// XOR-swizzled LDS accessors. byte ^= (row&7)<<4.
__device__ __forceinline__ bf16x8 lds_loadA(const __bf16* base, int row, int kByte, int rowBytes) {
  int off = (row * rowBytes + kByte) ^ ((row & 7) << 4);
  return *reinterpret_cast<const bf16x8*>(reinterpret_cast<const char*>(base) + off);
}
__device__ __forceinline__ void lds_store_bf16(__bf16* base, int row, int col, __bf16 v) {
  int off = (row * 512 + col * 2) ^ ((row & 7) << 4);  // 256-col tiles only
  *reinterpret_cast<__bf16*>(reinterpret_cast<char*>(base) + off) = v;
}

// LDS pool (bytes). Aliased regions with phase-disjoint lifetimes:
//   P_ADO2  [0,40960)      : ado activations, 80x512 swz (written ph4/ph6)
//     P_EGOIN [0,2048)     : ego input 16x128 swz   (dead after ph2)
//     P_EGOH1 [2048,10240) : ego hidden1 16x512 swz (dead after ph3)
//     P_ADOIN [24576,29696): ado input 80x64 swz    (dead after ph5)
//   P_EGOH2 [40960,49152)  : ego hidden2 16x512 swz (dead after ph4 'sel')
//     P_PROJIN (same addr) : proj input 16x512 swz  (written ph7)
//   P_H1    [49152,73728)  : ado hidden1 half, 48x512 swz (dead after ph6)
//     P_OBSRAW (same addr) : raw fp32 obs 16x168    (dead after ph1b)
//   P_OUT   [73728,77824)  : logit exchange (ph7) then proj fp32 out (ph8)
#define P_ADO2   0
#define P_EGOIN  0
#define P_EGOH1  2048
#define P_ADOIN  24576
#define P_EGOH2  40960
#define P_PROJIN 40960
#define P_H1     49152
#define P_OBSRAW 49152
#define P_OUT    73728
#define POOL_BYTES 77824   // 76KB -> 2 blocks/CU (152KB of 160KB)

// C(out 16R rows x 32 cols/wave) = act(A @ WT^T + bias). Column-split:
// wave w owns cols w*32 + c2*16 + lr. Each B fragment read once per block.
template<int KP, int R, bool ACT>
__device__ __forceinline__ void gemm_block(const __bf16* __restrict__ sA, int aRow0,
                                           __bf16* __restrict__ sC, int cRow0,
                                           const __bf16* __restrict__ WT,
                                           const float* __restrict__ bias,
                                           int w, int lr, int lg)
{
  constexpr int NKB = KP / 32;
  f32x4 acc[R][2];
  #pragma unroll
  for (int t = 0; t < R; ++t) {
    acc[t][0] = f32x4{0.f,0.f,0.f,0.f};
    acc[t][1] = f32x4{0.f,0.f,0.f,0.f};
  }
  #pragma unroll
  for (int kb = 0; kb < NKB; ++kb) {
    bf16x8 af[R];
    #pragma unroll
    for (int t = 0; t < R; ++t)
      af[t] = lds_loadA(sA, aRow0 + t*16 + lr, kb*64 + lg*16, KP*2);
    #pragma unroll
    for (int c2 = 0; c2 < 2; ++c2) {
      const int col = w*32 + c2*16 + lr;
      bf16x8 bfr = *reinterpret_cast<const bf16x8*>(WT + col*KP + kb*32 + lg*8);
      #pragma unroll
      for (int t = 0; t < R; ++t)
        acc[t][c2] = __builtin_amdgcn_mfma_f32_16x16x32_bf16(af[t], bfr, acc[t][c2], 0, 0, 0);
    }
  }
  #pragma unroll
  for (int c2 = 0; c2 < 2; ++c2) {
    const int col = w*32 + c2*16 + lr;
    const float bv = bias[col];
    #pragma unroll
    for (int t = 0; t < R; ++t) {
      #pragma unroll
      for (int e = 0; e < 4; ++e) {
        float x = acc[t][c2][e] + bv;
        if (ACT) x = x > 0.f ? x : 0.01f * x;
        lds_store_bf16(sC, cRow0 + t*16 + lg*4 + e, col, (__bf16)x);
      }
    }
  }
}

__global__ __launch_bounds__(512, 4) void fused_kernel(
    const float* __restrict__ obs,
    const float* __restrict__ eb0, const float* __restrict__ eb1,
    const float* __restrict__ ab0, const float* __restrict__ ab1,
    const float* __restrict__ latb, const float* __restrict__ projb,
    const __bf16* __restrict__ ws,
    float* __restrict__ out)
{
  const int tid = threadIdx.x;
  const int w  = tid >> 6;   // 8 waves
  const int l  = tid & 63;
  const int lr = l & 15;
  const int lg = l >> 4;
  const int b0 = blockIdx.x * 16;

  __shared__ __align__(16) char pool[POOL_BYTES];
  __bf16* sEgoIn = reinterpret_cast<__bf16*>(pool + P_EGOIN);
  __bf16* sEgoH1 = reinterpret_cast<__bf16*>(pool + P_EGOH1);
  __bf16* sAdoIn = reinterpret_cast<__bf16*>(pool + P_ADOIN);
  __bf16* sEgoH2 = reinterpret_cast<__bf16*>(pool + P_EGOH2);
  __bf16* sProj  = reinterpret_cast<__bf16*>(pool + P_PROJIN);
  __bf16* sAdo2  = reinterpret_cast<__bf16*>(pool + P_ADO2);
  __bf16* sH1    = reinterpret_cast<__bf16*>(pool + P_H1);
  float*  sObsF  = reinterpret_cast<float*>(pool + P_OBSRAW);
  float*  sLogF  = reinterpret_cast<float*>(pool + P_OUT);
  float*  sOutF  = reinterpret_cast<float*>(pool + P_OUT);

  // ---- phase 1a: coalesced obs -> LDS (fp32) + NT fp32 passthrough out[:, :48]
  {
    const f32x4* o4 = reinterpret_cast<const f32x4*>(obs);
    #pragma unroll
    for (int idx = tid; idx < 672; idx += 512) {   // 16 rows x 42 f32x4
      int row = idx / 42, c4 = idx % 42;
      f32x4 v = o4[(size_t)(b0+row)*42 + c4];
      *reinterpret_cast<f32x4*>(sObsF + row*168 + c4*4) = v;
      if (c4 < 12)
        __builtin_nontemporal_store(v,
            reinterpret_cast<f32x4*>(out + (size_t)(b0+row)*112 + c4*4));
    }
  }
  __syncthreads();

  // ---- phase 1b: build bf16 inputs from LDS fp32
  {
    if (tid < 192) {            // ego: 16 rows x 12 f32x4
      int row = tid / 12, c4 = tid % 12;
      f32x4 v = *reinterpret_cast<const f32x4*>(sObsF + row*168 + c4*4);
      bf16x4 bv = { (__bf16)v[0], (__bf16)v[1], (__bf16)v[2], (__bf16)v[3] };
      int off = (row*128 + c4*8) ^ ((row&7)<<4);
      *reinterpret_cast<bf16x4*>(reinterpret_cast<char*>(sEgoIn) + off) = bv;
    } else if (tid < 256) {     // ego zero pad cols 48..63
      int t = tid - 192;
      int row = t >> 2, ch = t & 3;
      bf16x4 z = {};
      int off = (row*128 + 96 + ch*8) ^ ((row&7)<<4);
      *reinterpret_cast<bf16x4*>(reinterpret_cast<char*>(sEgoIn) + off) = z;
    }
    if (tid >= 256 && tid < 496) {  // ado gather: 80 lds rows x 3 chunks of 8
      int t = tid - 256;
      int ldsrow = t / 3, p = t % 3;
      int n = ldsrow >> 4, r = ldsrow & 15;
      const float* orow = sObsF + r*168 + 48;
      bf16x8 v;
      #pragma unroll
      for (int j = 0; j < 8; ++j) v[j] = (__bf16)orow[(p*8+j)*5 + n];
      int off = (ldsrow*64 + p*16) ^ ((ldsrow&7)<<4);
      *reinterpret_cast<bf16x8*>(reinterpret_cast<char*>(sAdoIn) + off) = v;
    }
    if (tid >= 432) {               // cols 24..31: teamid + zero pad
      int t = tid - 432;            // 0..79
      int n = t >> 4;
      bf16x8 v = {};
      v[0] = (__bf16)((n >= 2) ? 1.0f : 0.0f);   // team_ids[1:6] = 0,0,1,1,1
      int off = (t*64 + 48) ^ ((t&7)<<4);
      *reinterpret_cast<bf16x8*>(reinterpret_cast<char*>(sAdoIn) + off) = v;
    }
  }
  __syncthreads();

  // ---- phase 2: ego0 + ado0 (agents 0..2 -> sH1 rows 0..47)
  gemm_block<64, 1, true>(sEgoIn, 0, sEgoH1, 0, ws + OFF_EGO0, eb0, w, lr, lg);
  gemm_block<32, 3, true>(sAdoIn, 0, sH1,    0, ws + OFF_ADO0, ab0, w, lr, lg);
  __syncthreads();

  // ---- phase 3: ego1
  gemm_block<256, 1, true>(sEgoH1, 0, sEgoH2, 0, ws + OFF_EGO1, eb1, w, lr, lg);
  __syncthreads();

  // ---- phase 4: sel (regs, 1/8 folded) + ado1 agents 0..2 -> sAdo2 rows 0..47
  f32x4 slct[2];
  {
    const __bf16* WT = ws + OFF_SEL;
    slct[0] = f32x4{0.f,0.f,0.f,0.f};
    slct[1] = f32x4{0.f,0.f,0.f,0.f};
    #pragma unroll
    for (int kb = 0; kb < 8; ++kb) {
      bf16x8 af = lds_loadA(sEgoH2, lr, kb*64 + lg*16, 512);
      #pragma unroll
      for (int c2 = 0; c2 < 2; ++c2) {
        bf16x8 bfr = *reinterpret_cast<const bf16x8*>(WT + (w*32+c2*16+lr)*256 + kb*32 + lg*8);
        slct[c2] = __builtin_amdgcn_mfma_f32_16x16x32_bf16(af, bfr, slct[c2], 0, 0, 0);
      }
    }
    slct[0] *= 0.125f;   // fold 1/sqrt(AD) into slct
    slct[1] *= 0.125f;
  }
  gemm_block<256, 3, true>(sH1, 0, sAdo2, 0, ws + OFF_ADO1, ab1, w, lr, lg);
  __syncthreads();

  // ---- phase 5: ado0 agents 3..4 -> sH1 rows 0..31
  gemm_block<32, 2, true>(sAdoIn, 48, sH1, 0, ws + OFF_ADO0, ab0, w, lr, lg);
  __syncthreads();

  // ---- phase 6: ado1 agents 3..4 -> sAdo2 rows 48..79
  gemm_block<256, 2, true>(sH1, 0, sAdo2, 48, ws + OFF_ADO1, ab1, w, lr, lg);
  __syncthreads();

  // ---- phase 7a: key pass, kb-outer, af[5] hoisted across both c2 halves.
  // kacc[5][2] (40 VGPR) + af[5] (20) raises live state so the allocator
  // targets 4 waves/EU (128 regs) and can pipeline B loads across kb.
  f32x4 part[5];
  {
    const __bf16* WK = ws + OFF_KEY;
    f32x4 kacc[5][2];
    #pragma unroll
    for (int n = 0; n < 5; ++n) {
      kacc[n][0] = f32x4{0.f,0.f,0.f,0.f};
      kacc[n][1] = f32x4{0.f,0.f,0.f,0.f};
    }
    #pragma unroll
    for (int kb = 0; kb < 8; ++kb) {
      bf16x8 af[5];
      #pragma unroll
      for (int n = 0; n < 5; ++n)
        af[n] = lds_loadA(sAdo2, n*16 + lr, kb*64 + lg*16, 512);
      #pragma unroll
      for (int c2 = 0; c2 < 2; ++c2) {
        bf16x8 bk = *reinterpret_cast<const bf16x8*>(
            WK + (w*32 + c2*16 + lr)*256 + kb*32 + lg*8);
        #pragma unroll
        for (int n = 0; n < 5; ++n)
          kacc[n][c2] = __builtin_amdgcn_mfma_f32_16x16x32_bf16(af[n], bk, kacc[n][c2], 0, 0, 0);
      }
    }
    #pragma unroll
    for (int n = 0; n < 5; ++n)
      part[n] = kacc[n][0]*slct[0] + kacc[n][1]*slct[1];
  }
  // reduce over lr lanes (sum over this wave's 32 d-dims)
  #pragma unroll
  for (int n = 0; n < 5; ++n) {
    #pragma unroll
    for (int m = 1; m < 16; m <<= 1) {
      part[n][0] += __shfl_xor(part[n][0], m);
      part[n][1] += __shfl_xor(part[n][1], m);
      part[n][2] += __shfl_xor(part[n][2], m);
      part[n][3] += __shfl_xor(part[n][3], m);
    }
  }
  // publish wave partials: sLogF[w][n][row] (f32x4 per (w,n,lg))
  #pragma unroll
  for (int n = 0; n < 5; ++n)
    if (lr == n)
      *reinterpret_cast<f32x4*>(sLogF + (w*5 + n)*16 + lg*4) = part[n];
  __syncthreads();
  // full logits = this wave's partial + partner wave's partial; exact softmax
  f32x4 p[5];
  {
    f32x4 lt[5];
    #pragma unroll
    for (int n = 0; n < 5; ++n)
      lt[n] = *reinterpret_cast<const f32x4*>(sLogF + (w*5 + n)*16 + lg*4)
            + *reinterpret_cast<const f32x4*>(sLogF + ((w^1)*5 + n)*16 + lg*4);
    f32x4 mx = lt[0];
    #pragma unroll
    for (int n = 1; n < 5; ++n)
      #pragma unroll
      for (int e = 0; e < 4; ++e) mx[e] = fmaxf(mx[e], lt[n][e]);
    f32x4 s = f32x4{0.f,0.f,0.f,0.f};
    #pragma unroll
    for (int n = 0; n < 5; ++n) {
      #pragma unroll
      for (int e = 0; e < 4; ++e) p[n][e] = __expf(lt[n][e] - mx[e]);
      s += p[n];
    }
    f32x4 inv;
    #pragma unroll
    for (int e = 0; e < 4; ++e) inv[e] = 1.0f / s[e];
    #pragma unroll
    for (int n = 0; n < 5; ++n) p[n] *= inv;
  }

  // ---- phase 7b: lat pass, same kb-outer/af-hoisted shape; agg in regs
  f32x4 agg[2];
  agg[0] = f32x4{0.f,0.f,0.f,0.f};
  agg[1] = f32x4{0.f,0.f,0.f,0.f};
  {
    const __bf16* WL = ws + OFF_LAT;
    f32x4 lacc[5][2];
    #pragma unroll
    for (int n = 0; n < 5; ++n) {
      lacc[n][0] = f32x4{0.f,0.f,0.f,0.f};
      lacc[n][1] = f32x4{0.f,0.f,0.f,0.f};
    }
    #pragma unroll
    for (int kb = 0; kb < 8; ++kb) {
      bf16x8 af[5];
      #pragma unroll
      for (int n = 0; n < 5; ++n)
        af[n] = lds_loadA(sAdo2, n*16 + lr, kb*64 + lg*16, 512);
      #pragma unroll
      for (int c2 = 0; c2 < 2; ++c2) {
        bf16x8 bl = *reinterpret_cast<const bf16x8*>(
            WL + (w*32 + c2*16 + lr)*256 + kb*32 + lg*8);
        #pragma unroll
        for (int n = 0; n < 5; ++n)
          lacc[n][c2] = __builtin_amdgcn_mfma_f32_16x16x32_bf16(af[n], bl, lacc[n][c2], 0, 0, 0);
      }
    }
    #pragma unroll
    for (int c2 = 0; c2 < 2; ++c2) {
      const float lb = latb[w*32 + c2*16 + lr];
      #pragma unroll
      for (int n = 0; n < 5; ++n) {
        #pragma unroll
        for (int e = 0; e < 4; ++e) {
          float x = lacc[n][c2][e] + lb;
          x = x > 0.f ? x : 0.01f * x;
          agg[c2][e] += p[n][e] * x;
        }
      }
    }
  }
  // agg -> sProj (proj input, bf16 swz). Overwrites sEgoH2 (dead).
  #pragma unroll
  for (int c2 = 0; c2 < 2; ++c2)
    #pragma unroll
    for (int e = 0; e < 4; ++e)
      lds_store_bf16(sProj, lg*4 + e, w*32 + c2*16 + lr, (__bf16)agg[c2][e]);
  __syncthreads();

  // ---- phase 8: proj (16x256)@(256x64); waves 0..3 -> cols w*16..w*16+15
  if (w < 4) {
    const __bf16* WT = ws + OFF_PROJ;
    f32x4 pacc = f32x4{0.f,0.f,0.f,0.f};
    #pragma unroll
    for (int kb = 0; kb < 8; ++kb) {
      bf16x8 af = lds_loadA(sProj, lr, kb*64 + lg*16, 512);
      bf16x8 bfr = *reinterpret_cast<const bf16x8*>(WT + (w*16+lr)*256 + kb*32 + lg*8);
      pacc = __builtin_amdgcn_mfma_f32_16x16x32_bf16(af, bfr, pacc, 0, 0, 0);
    }
    const float pb = projb[w*16 + lr];
    #pragma unroll
    for (int e = 0; e < 4; ++e)
      sOutF[(lg*4 + e)*64 + w*16 + lr] = pacc[e] + pb;
  }
  __syncthreads();

  // ---- phase 9: coalesced NT float4 writes of out[:, 48:112]
  if (tid < 256) {
    int row = tid >> 4, q = tid & 15;
    f32x4 v = *reinterpret_cast<const f32x4*>(sOutF + row*64 + q*4);
    __builtin_nontemporal_store(v,
        reinterpret_cast<f32x4*>(out + (size_t)(b0+row)*112 + 48 + q*4));
  }
}

extern "C" void kernel_launch(void* const* d_in, const int* in_sizes, int n_in,
                              void* d_out, int out_size, void* d_ws, size_t ws_size,
                              hipStream_t stream) {
  const float* obs   = (const float*)d_in[0];
  const float* ew0   = (const float*)d_in[1];
  const float* eb0   = (const float*)d_in[2];
  const float* ew1   = (const float*)d_in[3];
  const float* eb1   = (const float*)d_in[4];
  const float* aw0   = (const float*)d_in[5];
  const float* ab0   = (const float*)d_in[6];
  const float* aw1   = (const float*)d_in[7];
  const float* ab1   = (const float*)d_in[8];
  const float* keyw  = (const float*)d_in[9];
  const float* selw  = (const float*)d_in[10];
  const float* latw  = (const float*)d_in[11];
  const float* latb  = (const float*)d_in[12];
  const float* projw = (const float*)d_in[13];
  const float* projb = (const float*)d_in[14];
  __bf16* ws = (__bf16*)d_ws;
  float* out = (float*)d_out;

  prep_weights<<<dim3((WS_ELEMS + 255)/256), dim3(256), 0, stream>>>(
      ew0, ew1, aw0, aw1, keyw, selw, latw, projw, ws);
  fused_kernel<<<dim3(65536/16), dim3(512), 0, stream>>>(
      obs, eb0, eb1, ab0, ab1, latb, projb, ws, out);
}